// Round 2
// baseline (3731.004 us; speedup 1.0000x reference)
//
#include <hip/hip_runtime.h>
#include <cstdint>
#include <cstddef>

// ---------------------------------------------------------------------------
// Sememe-LSTM, T=256 B=64 I=M=512.
// Phase A: one f16 MFMA GEMM [16384,1024] @ [1024,2560] computing every
//          non-recurrent term, epilogue stores f16 pre[t][g][m][b] and
//          addc[t][m][b] (= sigmoid(fs_raw)*sememe_c, fully precomputable).
// Phase B: persistent 64-WG kernel, 256 serial steps. Inter-WG sync via a
//          DISTRIBUTED FLAG BARRIER (one 64B-padded epoch flag per WG,
//          release-store + all-wave 64-lane gather poll) — the round-1
//          single-counter atomic RMW serialized 64 cross-XCD RMWs/step
//          (~13.6us/step, 98% idle). No RMW at all now.
// ---------------------------------------------------------------------------

typedef _Float16 half8 __attribute__((ext_vector_type(8)));
typedef _Float16 half4 __attribute__((ext_vector_type(4)));
typedef float    f32x4 __attribute__((ext_vector_type(4)));

#define T_STEPS 256
#define B_DIM   64
#define M_DIM   512
#define KA      1024          // combined K (x | sememe_h)
#define NA      2560          // combined N (iou 1536 | f 512 | fs 512)
#define MA      16384         // T*B
#define NWG_REC 64
#define FLAG_STRIDE 16        // ints -> 64B per flag, one cache line each

__device__ __forceinline__ float sigmoidf_fast(float x) {
    return 1.0f / (1.0f + __expf(-x));
}
__device__ __forceinline__ float tanhf_fast(float x) {
    float e = __expf(2.0f * x);
    return 1.0f - 2.0f / (e + 1.0f);
}

// ---------------- conversion kernels (f32 -> f16 packing) -------------------

__global__ void conv_xs(const float* __restrict__ inp, const float* __restrict__ sh,
                        _Float16* __restrict__ xs) {
    int idx = blockIdx.x * blockDim.x + threadIdx.x;   // one 8-elem chunk
    const int total = MA * KA / 8;
    if (idx >= total) return;
    int row = idx >> 7;
    int col = (idx & 127) * 8;
    const float* src = (col < 512) ? (inp + (size_t)row * 512 + col)
                                   : (sh  + (size_t)row * 512 + (col - 512));
    f32x4 a = *(const f32x4*)src;
    f32x4 b = *(const f32x4*)(src + 4);
    half8 o;
    o[0]=(_Float16)a[0]; o[1]=(_Float16)a[1]; o[2]=(_Float16)a[2]; o[3]=(_Float16)a[3];
    o[4]=(_Float16)b[0]; o[5]=(_Float16)b[1]; o[6]=(_Float16)b[2]; o[7]=(_Float16)b[3];
    *(half8*)(xs + (size_t)idx * 8) = o;
}

__global__ void conv_w(const float* __restrict__ W_ioux, const float* __restrict__ W_ious,
                       const float* __restrict__ W_fx,   const float* __restrict__ W_fxs,
                       const float* __restrict__ W_fs,   _Float16* __restrict__ wc) {
    int idx = blockIdx.x * blockDim.x + threadIdx.x;
    const int total = NA * KA / 8;
    if (idx >= total) return;
    int n = idx >> 7;
    int col = (idx & 127) * 8;
    const float* src = nullptr;
    if (col < 512) {
        int k = col;
        src = (n < 1536) ? (W_ioux + (size_t)n * 512 + k)
            : (n < 2048) ? (W_fx   + (size_t)(n - 1536) * 512 + k)
                         : (W_fxs  + (size_t)(n - 2048) * 512 + k);
    } else {
        int k = col - 512;
        if (n < 1536)      src = W_ious + (size_t)n * 512 + k;
        else if (n >= 2048) src = W_fs  + (size_t)(n - 2048) * 512 + k;
        // else: zero block (f gate has no sememe term)
    }
    half8 o;
    if (src) {
        f32x4 a = *(const f32x4*)src;
        f32x4 b = *(const f32x4*)(src + 4);
        o[0]=(_Float16)a[0]; o[1]=(_Float16)a[1]; o[2]=(_Float16)a[2]; o[3]=(_Float16)a[3];
        o[4]=(_Float16)b[0]; o[5]=(_Float16)b[1]; o[6]=(_Float16)b[2]; o[7]=(_Float16)b[3];
    } else {
        #pragma unroll
        for (int i = 0; i < 8; ++i) o[i] = (_Float16)0.0f;
    }
    *(half8*)(wc + (size_t)idx * 8) = o;
}

__global__ void conv_wr(const float* __restrict__ W_iouh, const float* __restrict__ W_fh,
                        _Float16* __restrict__ wr) {
    int idx = blockIdx.x * blockDim.x + threadIdx.x;
    const int total = 2048 * 512 / 8;
    if (idx >= total) return;
    int n = idx >> 6;
    int col = (idx & 63) * 8;
    int wgs = n >> 5, loc = n & 31;
    int g = (loc >> 4) * 2 + ((loc >> 3) & 1);
    int m = wgs * 8 + (loc & 7);
    const float* src = (g < 3) ? (W_iouh + ((size_t)(g * 512 + m)) * 512 + col)
                               : (W_fh   + (size_t)m * 512 + col);
    f32x4 a = *(const f32x4*)src;
    f32x4 b = *(const f32x4*)(src + 4);
    half8 o;
    o[0]=(_Float16)a[0]; o[1]=(_Float16)a[1]; o[2]=(_Float16)a[2]; o[3]=(_Float16)a[3];
    o[4]=(_Float16)b[0]; o[5]=(_Float16)b[1]; o[6]=(_Float16)b[2]; o[7]=(_Float16)b[3];
    *(half8*)(wr + (size_t)idx * 8) = o;
}

__global__ void conv_h0(const float* __restrict__ h0, _Float16* __restrict__ hb) {
    int idx = blockIdx.x * blockDim.x + threadIdx.x;
    const int total = B_DIM * M_DIM / 8;
    if (idx >= total) return;
    f32x4 a = *(const f32x4*)(h0 + (size_t)idx * 8);
    f32x4 b = *(const f32x4*)(h0 + (size_t)idx * 8 + 4);
    half8 o;
    o[0]=(_Float16)a[0]; o[1]=(_Float16)a[1]; o[2]=(_Float16)a[2]; o[3]=(_Float16)a[3];
    o[4]=(_Float16)b[0]; o[5]=(_Float16)b[1]; o[6]=(_Float16)b[2]; o[7]=(_Float16)b[3];
    *(half8*)(hb + (size_t)idx * 8) = o;
}

// ---------------- Phase A: big GEMM + fused epilogue ------------------------

__global__ __launch_bounds__(256, 2)
void gemm_pre(const _Float16* __restrict__ A, const _Float16* __restrict__ W,
              const float* __restrict__ b_ioux, const float* __restrict__ b_iouh,
              const float* __restrict__ b_ious, const float* __restrict__ b_fx,
              const float* __restrict__ b_fh,   const float* __restrict__ b_fxs,
              const float* __restrict__ b_fs,   const float* __restrict__ smc,
              _Float16* __restrict__ pre, _Float16* __restrict__ addc) {
    __shared__ _Float16 As[128 * 64];
    __shared__ _Float16 Bs[128 * 64];

    const int nwg = 2560;
    int orig = blockIdx.x;
    int wgid = (orig & 7) * (nwg >> 3) + (orig >> 3);   // XCD-aware swizzle (2560%8==0)
    const int bx = wgid & 127;       // M tile (128 of them)
    const int by = wgid >> 7;        // N tile (20)
    const int m0 = bx * 128, n0 = by * 128;

    const int tid = threadIdx.x;
    const int wv = tid >> 6, lane = tid & 63;
    const int lr = lane & 15, lq = lane >> 4;
    const int wr = wv >> 1, wc = wv & 1;

    f32x4 acc[4][4];
    #pragma unroll
    for (int i = 0; i < 4; ++i)
        #pragma unroll
        for (int j = 0; j < 4; ++j)
            #pragma unroll
            for (int r = 0; r < 4; ++r) acc[i][j][r] = 0.0f;

    for (int kt = 0; kt < KA / 64; ++kt) {
        const int k0 = kt * 64;
        #pragma unroll
        for (int j = 0; j < 4; ++j) {
            int L = j * 4096 + wv * 1024 + lane * 16;       // linear LDS byte
            int row = L >> 7;
            int colb = (L & 127) ^ ((row & 7) << 4);        // inverse-swizzled source
            const char* ga = (const char*)(A + (size_t)(m0 + row) * KA + k0) + colb;
            __builtin_amdgcn_global_load_lds(
                (const __attribute__((address_space(1))) void*)ga,
                (__attribute__((address_space(3))) void*)((char*)As + j * 4096 + wv * 1024),
                16, 0, 0);
            const char* gb = (const char*)(W + (size_t)(n0 + row) * KA + k0) + colb;
            __builtin_amdgcn_global_load_lds(
                (const __attribute__((address_space(1))) void*)gb,
                (__attribute__((address_space(3))) void*)((char*)Bs + j * 4096 + wv * 1024),
                16, 0, 0);
        }
        __syncthreads();

        half8 af[4][2], bf[4][2];
        #pragma unroll
        for (int f = 0; f < 4; ++f) {
            #pragma unroll
            for (int kk = 0; kk < 2; ++kk) {
                {
                    int row = wr * 64 + f * 16 + lr;
                    int byt = row * 128 + (((kk * 32 + lq * 8) * 2) ^ ((row & 7) << 4));
                    af[f][kk] = *(const half8*)((const char*)As + byt);
                }
                {
                    int row = wc * 64 + f * 16 + lr;
                    int byt = row * 128 + (((kk * 32 + lq * 8) * 2) ^ ((row & 7) << 4));
                    bf[f][kk] = *(const half8*)((const char*)Bs + byt);
                }
            }
        }
        #pragma unroll
        for (int kk = 0; kk < 2; ++kk)
            #pragma unroll
            for (int fi = 0; fi < 4; ++fi)
                #pragma unroll
                for (int fj = 0; fj < 4; ++fj)
                    acc[fi][fj] = __builtin_amdgcn_mfma_f32_16x16x32_f16(
                        af[fi][kk], bf[fj][kk], acc[fi][fj], 0, 0, 0);
        __syncthreads();
    }

    // Epilogue: D layout col=lane&15, row=(lane>>4)*4+reg.
    #pragma unroll
    for (int fi = 0; fi < 4; ++fi) {
        int row0 = m0 + wr * 64 + fi * 16 + lq * 4;  // 4 consecutive tb rows
        int tt = row0 >> 6;
        int b  = row0 & 63;
        #pragma unroll
        for (int fj = 0; fj < 4; ++fj) {
            int col = n0 + wc * 64 + fj * 16 + lr;
            f32x4 v = acc[fi][fj];
            if (col < 2048) {
                int g, mm; float bias;
                if (col < 1536) { g = col >> 9; mm = col & 511;
                                  bias = b_ioux[col] + b_iouh[col] + b_ious[col]; }
                else            { g = 3; mm = col - 1536; bias = b_fx[mm] + b_fh[mm]; }
                half4 hv;
                #pragma unroll
                for (int r = 0; r < 4; ++r) hv[r] = (_Float16)(v[r] + bias);
                *(half4*)(pre + ((((size_t)tt * 4 + g) * 512 + mm) * 64 + b)) = hv;
            } else {
                int mm = col - 2048;
                float bias = b_fxs[mm] + b_fs[mm];
                half4 hv;
                #pragma unroll
                for (int r = 0; r < 4; ++r) {
                    float s  = sigmoidf_fast(v[r] + bias);
                    float sc = smc[((size_t)(tt * 64 + b + r)) * 512 + mm];
                    hv[r] = (_Float16)(s * sc);
                }
                *(half4*)(addc + (((size_t)tt * 512 + mm) * 64 + b)) = hv;
            }
        }
    }
}

// ---------------- Phase B: persistent recurrent kernel ----------------------
// 64 WGs x 256 threads. WG owns m in [wg*8, wg*8+8); wave v owns b-tile
// [v*16, v*16+16). N-slice = 32 cols: {i x8, o x8} (ntile0), {u x8, f x8}
// (ntile1). Lane l: c8=(l>>3)&1 splits lane pairs l / l^8 into (i,u)/(o,f).
// Weights in registers. Step barrier: per-WG 64B-padded epoch flags,
// release-store own flag; every wave gather-polls all 64 flags (no RMW,
// no trailing syncthreads). out[t] stores hide inside the wait window.

__global__ __launch_bounds__(256, 1)
void lstm_rec(const _Float16* __restrict__ Wr, const _Float16* __restrict__ pre,
              const _Float16* __restrict__ addc, const float* __restrict__ c0,
              _Float16* __restrict__ hbuf, float* __restrict__ out,
              int* __restrict__ flags) {
    const int wg = blockIdx.x;
    const int tid = threadIdx.x;
    const int wv = tid >> 6, lane = tid & 63;
    const int lr = lane & 15, lq = lane >> 4;
    const int c8 = (lane >> 3) & 1;
    const int m  = wg * 8 + (lane & 7);
    const int b0 = wv * 16 + lq * 4;

    // recurrent weights -> registers (once)
    half8 bfr[2][16];
    #pragma unroll
    for (int nt = 0; nt < 2; ++nt)
        #pragma unroll
        for (int kk = 0; kk < 16; ++kk)
            bfr[nt][kk] = *(const half8*)(Wr + ((size_t)(wg * 32 + nt * 16 + lr)) * 512
                                          + kk * 32 + lq * 8);

    float c[4];
    #pragma unroll
    for (int r = 0; r < 4; ++r) c[r] = c0[(size_t)(b0 + r) * 512 + m];

    half4 pv[2], av;
    #pragma unroll
    for (int nt = 0; nt < 2; ++nt) {
        int g = nt * 2 + c8;
        pv[nt] = *(const half4*)(pre + (((size_t)0 * 4 + g) * 512 + m) * 64 + b0);
    }
    av = *(const half4*)(addc + ((size_t)0 * 512 + m) * 64 + b0);

    for (int t = 0; t < T_STEPS; ++t) {
        const _Float16* hr = hbuf + (size_t)(t & 1) * B_DIM * M_DIM;

        half8 af[16];
        #pragma unroll
        for (int kk = 0; kk < 16; ++kk)
            af[kk] = *(const half8*)(hr + (size_t)(wv * 16 + lr) * 512 + kk * 32 + lq * 8);

        f32x4 acc[2];
        #pragma unroll
        for (int nt = 0; nt < 2; ++nt)
            #pragma unroll
            for (int r = 0; r < 4; ++r) acc[nt][r] = (float)pv[nt][r];
        half4 avc = av;

        // prefetch next step's pre/addc (latency hidden under MFMA+elementwise)
        if (t + 1 < T_STEPS) {
            #pragma unroll
            for (int nt = 0; nt < 2; ++nt) {
                int g = nt * 2 + c8;
                pv[nt] = *(const half4*)(pre + (((size_t)(t + 1) * 4 + g) * 512 + m) * 64 + b0);
            }
            av = *(const half4*)(addc + ((size_t)(t + 1) * 512 + m) * 64 + b0);
        }

        #pragma unroll
        for (int kk = 0; kk < 16; ++kk) {
            acc[0] = __builtin_amdgcn_mfma_f32_16x16x32_f16(af[kk], bfr[0][kk], acc[0], 0, 0, 0);
            acc[1] = __builtin_amdgcn_mfma_f32_16x16x32_f16(af[kk], bfr[1][kk], acc[1], 0, 0, 0);
        }

        float hnew[4];
        #pragma unroll
        for (int r = 0; r < 4; ++r) {
            float raw0 = acc[0][r];   // laneA: i_raw  | laneB: o_raw
            float raw1 = acc[1][r];   // laneA: u_raw  | laneB: f_raw
            float s0 = sigmoidf_fast(raw0);
            float v1 = c8 ? sigmoidf_fast(raw1) : tanhf_fast(raw1);
            float sf = __shfl_xor(v1, 8);               // laneA <- sig(f)
            float cn = s0 * v1 + sf * c[r] + (float)avc[r];   // valid on laneA
            float tc = tanhf_fast(cn);
            float tcx = __shfl_xor(tc, 8);              // laneB <- tanh(c_new)
            if (!c8) c[r] = cn;
            hnew[r] = s0 * tcx;                         // valid on laneB
        }

        // publish h for step t+1 FIRST (only thing the barrier must order)
        _Float16* hw = hbuf + (size_t)((t + 1) & 1) * B_DIM * M_DIM;
        if (c8) {
            #pragma unroll
            for (int r = 0; r < 4; ++r)
                hw[(size_t)(b0 + r) * M_DIM + m] = (_Float16)hnew[r];
        }

        if (t == T_STEPS - 1) {
            if (c8) {
                #pragma unroll
                for (int r = 0; r < 4; ++r)
                    out[((size_t)t * B_DIM + b0 + r) * M_DIM + m] = hnew[r];
            }
            size_t base = (size_t)T_STEPS * B_DIM * M_DIM;
            if (!c8) {
                #pragma unroll
                for (int r = 0; r < 4; ++r)
                    out[base + (size_t)(b0 + r) * M_DIM + m] = c[r];
            } else {
                #pragma unroll
                for (int r = 0; r < 4; ++r)
                    out[base + (size_t)B_DIM * M_DIM + (size_t)(b0 + r) * M_DIM + m] = hnew[r];
            }
        } else {
            // ---- distributed flag barrier (no RMW) ----
            __threadfence();                 // each writer orders its h stores
            __syncthreads();                 // whole WG's h stores are fenced
            if (tid == 0)
                __hip_atomic_store(&flags[wg * FLAG_STRIDE], t + 1,
                                   __ATOMIC_RELEASE, __HIP_MEMORY_SCOPE_AGENT);
            // latency-hidden inside the wait window: out[t] stores
            if (c8) {
                #pragma unroll
                for (int r = 0; r < 4; ++r)
                    out[((size_t)t * B_DIM + b0 + r) * M_DIM + m] = hnew[r];
            }
            // every wave gather-polls all 64 flags (lane i <-> WG i)
            const int target = t + 1;
            while (true) {
                int v = __hip_atomic_load(&flags[lane * FLAG_STRIDE],
                                          __ATOMIC_ACQUIRE, __HIP_MEMORY_SCOPE_AGENT);
                if (__all(v >= target)) break;
                __builtin_amdgcn_s_sleep(1);
            }
            // no trailing __syncthreads: each wave self-releases
        }
    }
}

// ---------------------------------------------------------------------------

extern "C" void kernel_launch(void* const* d_in, const int* in_sizes, int n_in,
                              void* d_out, int out_size, void* d_ws, size_t ws_size,
                              hipStream_t stream) {
    const float* inputs  = (const float*)d_in[0];
    const float* smc     = (const float*)d_in[1];
    const float* smh     = (const float*)d_in[2];
    const float* c0      = (const float*)d_in[3];
    const float* h0      = (const float*)d_in[4];
    const float* W_ioux  = (const float*)d_in[5];
    const float* b_ioux  = (const float*)d_in[6];
    const float* W_iouh  = (const float*)d_in[7];
    const float* b_iouh  = (const float*)d_in[8];
    const float* W_ious  = (const float*)d_in[9];
    const float* b_ious  = (const float*)d_in[10];
    const float* W_fx    = (const float*)d_in[11];
    const float* b_fx    = (const float*)d_in[12];
    const float* W_fxs   = (const float*)d_in[13];
    const float* b_fxs   = (const float*)d_in[14];
    const float* W_fh    = (const float*)d_in[15];
    const float* b_fh    = (const float*)d_in[16];
    const float* W_fs    = (const float*)d_in[17];
    const float* b_fs    = (const float*)d_in[18];

    char* ws = (char*)d_ws;
    size_t off = 0;
    auto alloc = [&](size_t bytes) {
        char* p = ws + off;
        off = (off + bytes + 255) & ~(size_t)255;
        return p;
    };
    _Float16* XS   = (_Float16*)alloc((size_t)MA * KA * 2);          // 32 MiB
    _Float16* Wc   = (_Float16*)alloc((size_t)NA * KA * 2);          // 5 MiB
    _Float16* Wr   = (_Float16*)alloc((size_t)2048 * 512 * 2);       // 2 MiB
    _Float16* hb   = (_Float16*)alloc((size_t)2 * B_DIM * M_DIM * 2);// 128 KiB
    _Float16* pre  = (_Float16*)alloc((size_t)T_STEPS * 4 * 512 * 64 * 2); // 64 MiB
    _Float16* addc = (_Float16*)alloc((size_t)T_STEPS * 512 * 64 * 2);     // 16 MiB
    int* flags     = (int*)alloc(NWG_REC * FLAG_STRIDE * sizeof(int));     // 4 KiB
    if (off > ws_size) return;  // insufficient workspace -> visible failure

    hipMemsetAsync(flags, 0, NWG_REC * FLAG_STRIDE * sizeof(int), stream);
    conv_xs <<<MA * KA / 8 / 256, 256, 0, stream>>>(inputs, smh, XS);
    conv_w  <<<NA * KA / 8 / 256, 256, 0, stream>>>(W_ioux, W_ious, W_fx, W_fxs, W_fs, Wc);
    conv_wr <<<2048 * 512 / 8 / 256, 256, 0, stream>>>(W_iouh, W_fh, Wr);
    conv_h0 <<<B_DIM * M_DIM / 8 / 256, 256, 0, stream>>>(h0, hb);
    gemm_pre<<<2560, 256, 0, stream>>>(XS, Wc, b_ioux, b_iouh, b_ious, b_fx, b_fh,
                                       b_fxs, b_fs, smc, pre, addc);
    lstm_rec<<<NWG_REC, 256, 0, stream>>>(Wr, pre, addc, c0, hb, (float*)d_out, flags);
}

// Round 4
// 1324.652 us; speedup vs baseline: 2.8166x; 2.8166x over previous
//
#include <hip/hip_runtime.h>
#include <cstdint>
#include <cstddef>

// ---------------------------------------------------------------------------
// Sememe-LSTM, T=256 B=64 I=M=512.
// Phase A: one f16 MFMA GEMM [16384,1024] @ [1024,2560] computing every
//          non-recurrent term, epilogue stores f16 pre[t][g][m][b] and
//          addc[t][m][b] (= sigmoid(fs_raw)*sememe_c, fully precomputable).
// Phase B: persistent 64-WG kernel, 256 serial steps. No cache-maintenance
//          ops in the loop (R1/R2 lesson: AGENT acquire/release emit
//          buffer_inv/buffer_wbl2 = full per-XCD L2 walks per poll).
//          Cross-WG traffic (h, flags) via sc0+sc1 device-coherent accesses;
//          ordering via s_waitcnt vmcnt(0).
// R3 lessons: (1) acc-init MUST read pre/addc BEFORE the t+1 prefetch
//          clobbers pv/av (R3 consumed next-step values -> absmax 1.92);
//          (2) asm VMEM loads + separate waitcnt block allow compiler-
//          inserted v_movs to read not-ready dest regs -> monolithic asm
//          block (16 loads + s_waitcnt in ONE statement).
// ---------------------------------------------------------------------------

typedef _Float16 half8 __attribute__((ext_vector_type(8)));
typedef _Float16 half4 __attribute__((ext_vector_type(4)));
typedef float    f32x4 __attribute__((ext_vector_type(4)));

#define T_STEPS 256
#define B_DIM   64
#define M_DIM   512
#define KA      1024          // combined K (x | sememe_h)
#define NA      2560          // combined N (iou 1536 | f 512 | fs 512)
#define MA      16384         // T*B
#define NWG_REC 64
#define FLAG_STRIDE 32        // ints -> 128B per flag line

__device__ __forceinline__ float sigmoidf_fast(float x) {
    return 1.0f / (1.0f + __expf(-x));
}
__device__ __forceinline__ float tanhf_fast(float x) {
    float e = __expf(2.0f * x);
    return 1.0f - 2.0f / (e + 1.0f);
}

// ---------------- conversion kernels (f32 -> f16 packing) -------------------

__global__ void conv_xs(const float* __restrict__ inp, const float* __restrict__ sh,
                        _Float16* __restrict__ xs) {
    int idx = blockIdx.x * blockDim.x + threadIdx.x;   // one 8-elem chunk
    const int total = MA * KA / 8;
    if (idx >= total) return;
    int row = idx >> 7;
    int col = (idx & 127) * 8;
    const float* src = (col < 512) ? (inp + (size_t)row * 512 + col)
                                   : (sh  + (size_t)row * 512 + (col - 512));
    f32x4 a = *(const f32x4*)src;
    f32x4 b = *(const f32x4*)(src + 4);
    half8 o;
    o[0]=(_Float16)a[0]; o[1]=(_Float16)a[1]; o[2]=(_Float16)a[2]; o[3]=(_Float16)a[3];
    o[4]=(_Float16)b[0]; o[5]=(_Float16)b[1]; o[6]=(_Float16)b[2]; o[7]=(_Float16)b[3];
    *(half8*)(xs + (size_t)idx * 8) = o;
}

__global__ void conv_w(const float* __restrict__ W_ioux, const float* __restrict__ W_ious,
                       const float* __restrict__ W_fx,   const float* __restrict__ W_fxs,
                       const float* __restrict__ W_fs,   _Float16* __restrict__ wc) {
    int idx = blockIdx.x * blockDim.x + threadIdx.x;
    const int total = NA * KA / 8;
    if (idx >= total) return;
    int n = idx >> 7;
    int col = (idx & 127) * 8;
    const float* src = nullptr;
    if (col < 512) {
        int k = col;
        src = (n < 1536) ? (W_ioux + (size_t)n * 512 + k)
            : (n < 2048) ? (W_fx   + (size_t)(n - 1536) * 512 + k)
                         : (W_fxs  + (size_t)(n - 2048) * 512 + k);
    } else {
        int k = col - 512;
        if (n < 1536)      src = W_ious + (size_t)n * 512 + k;
        else if (n >= 2048) src = W_fs  + (size_t)(n - 2048) * 512 + k;
        // else: zero block (f gate has no sememe term)
    }
    half8 o;
    if (src) {
        f32x4 a = *(const f32x4*)src;
        f32x4 b = *(const f32x4*)(src + 4);
        o[0]=(_Float16)a[0]; o[1]=(_Float16)a[1]; o[2]=(_Float16)a[2]; o[3]=(_Float16)a[3];
        o[4]=(_Float16)b[0]; o[5]=(_Float16)b[1]; o[6]=(_Float16)b[2]; o[7]=(_Float16)b[3];
    } else {
        #pragma unroll
        for (int i = 0; i < 8; ++i) o[i] = (_Float16)0.0f;
    }
    *(half8*)(wc + (size_t)idx * 8) = o;
}

__global__ void conv_wr(const float* __restrict__ W_iouh, const float* __restrict__ W_fh,
                        _Float16* __restrict__ wr) {
    int idx = blockIdx.x * blockDim.x + threadIdx.x;
    const int total = 2048 * 512 / 8;
    if (idx >= total) return;
    int n = idx >> 6;
    int col = (idx & 63) * 8;
    int wgs = n >> 5, loc = n & 31;
    int g = (loc >> 4) * 2 + ((loc >> 3) & 1);
    int m = wgs * 8 + (loc & 7);
    const float* src = (g < 3) ? (W_iouh + ((size_t)(g * 512 + m)) * 512 + col)
                               : (W_fh   + (size_t)m * 512 + col);
    f32x4 a = *(const f32x4*)src;
    f32x4 b = *(const f32x4*)(src + 4);
    half8 o;
    o[0]=(_Float16)a[0]; o[1]=(_Float16)a[1]; o[2]=(_Float16)a[2]; o[3]=(_Float16)a[3];
    o[4]=(_Float16)b[0]; o[5]=(_Float16)b[1]; o[6]=(_Float16)b[2]; o[7]=(_Float16)b[3];
    *(half8*)(wr + (size_t)idx * 8) = o;
}

__global__ void conv_h0(const float* __restrict__ h0, _Float16* __restrict__ hb) {
    int idx = blockIdx.x * blockDim.x + threadIdx.x;
    const int total = B_DIM * M_DIM / 8;
    if (idx >= total) return;
    f32x4 a = *(const f32x4*)(h0 + (size_t)idx * 8);
    f32x4 b = *(const f32x4*)(h0 + (size_t)idx * 8 + 4);
    half8 o;
    o[0]=(_Float16)a[0]; o[1]=(_Float16)a[1]; o[2]=(_Float16)a[2]; o[3]=(_Float16)a[3];
    o[4]=(_Float16)b[0]; o[5]=(_Float16)b[1]; o[6]=(_Float16)b[2]; o[7]=(_Float16)b[3];
    *(half8*)(hb + (size_t)idx * 8) = o;
}

// ---------------- Phase A: big GEMM + fused epilogue ------------------------

__global__ __launch_bounds__(256, 2)
void gemm_pre(const _Float16* __restrict__ A, const _Float16* __restrict__ W,
              const float* __restrict__ b_ioux, const float* __restrict__ b_iouh,
              const float* __restrict__ b_ious, const float* __restrict__ b_fx,
              const float* __restrict__ b_fh,   const float* __restrict__ b_fxs,
              const float* __restrict__ b_fs,   const float* __restrict__ smc,
              _Float16* __restrict__ pre, _Float16* __restrict__ addc) {
    __shared__ _Float16 As[128 * 64];
    __shared__ _Float16 Bs[128 * 64];

    const int nwg = 2560;
    int orig = blockIdx.x;
    int wgid = (orig & 7) * (nwg >> 3) + (orig >> 3);   // XCD-aware swizzle (2560%8==0)
    const int bx = wgid & 127;       // M tile (128 of them)
    const int by = wgid >> 7;        // N tile (20)
    const int m0 = bx * 128, n0 = by * 128;

    const int tid = threadIdx.x;
    const int wv = tid >> 6, lane = tid & 63;
    const int lr = lane & 15, lq = lane >> 4;
    const int wr = wv >> 1, wc = wv & 1;

    f32x4 acc[4][4];
    #pragma unroll
    for (int i = 0; i < 4; ++i)
        #pragma unroll
        for (int j = 0; j < 4; ++j)
            #pragma unroll
            for (int r = 0; r < 4; ++r) acc[i][j][r] = 0.0f;

    for (int kt = 0; kt < KA / 64; ++kt) {
        const int k0 = kt * 64;
        #pragma unroll
        for (int j = 0; j < 4; ++j) {
            int L = j * 4096 + wv * 1024 + lane * 16;       // linear LDS byte
            int row = L >> 7;
            int colb = (L & 127) ^ ((row & 7) << 4);        // inverse-swizzled source
            const char* ga = (const char*)(A + (size_t)(m0 + row) * KA + k0) + colb;
            __builtin_amdgcn_global_load_lds(
                (const __attribute__((address_space(1))) void*)ga,
                (__attribute__((address_space(3))) void*)((char*)As + j * 4096 + wv * 1024),
                16, 0, 0);
            const char* gb = (const char*)(W + (size_t)(n0 + row) * KA + k0) + colb;
            __builtin_amdgcn_global_load_lds(
                (const __attribute__((address_space(1))) void*)gb,
                (__attribute__((address_space(3))) void*)((char*)Bs + j * 4096 + wv * 1024),
                16, 0, 0);
        }
        __syncthreads();

        half8 af[4][2], bf[4][2];
        #pragma unroll
        for (int f = 0; f < 4; ++f) {
            #pragma unroll
            for (int kk = 0; kk < 2; ++kk) {
                {
                    int row = wr * 64 + f * 16 + lr;
                    int byt = row * 128 + (((kk * 32 + lq * 8) * 2) ^ ((row & 7) << 4));
                    af[f][kk] = *(const half8*)((const char*)As + byt);
                }
                {
                    int row = wc * 64 + f * 16 + lr;
                    int byt = row * 128 + (((kk * 32 + lq * 8) * 2) ^ ((row & 7) << 4));
                    bf[f][kk] = *(const half8*)((const char*)Bs + byt);
                }
            }
        }
        #pragma unroll
        for (int kk = 0; kk < 2; ++kk)
            #pragma unroll
            for (int fi = 0; fi < 4; ++fi)
                #pragma unroll
                for (int fj = 0; fj < 4; ++fj)
                    acc[fi][fj] = __builtin_amdgcn_mfma_f32_16x16x32_f16(
                        af[fi][kk], bf[fj][kk], acc[fi][fj], 0, 0, 0);
        __syncthreads();
    }

    // Epilogue: D layout col=lane&15, row=(lane>>4)*4+reg.
    #pragma unroll
    for (int fi = 0; fi < 4; ++fi) {
        int row0 = m0 + wr * 64 + fi * 16 + lq * 4;  // 4 consecutive tb rows
        int tt = row0 >> 6;
        int b  = row0 & 63;
        #pragma unroll
        for (int fj = 0; fj < 4; ++fj) {
            int col = n0 + wc * 64 + fj * 16 + lr;
            f32x4 v = acc[fi][fj];
            if (col < 2048) {
                int g, mm; float bias;
                if (col < 1536) { g = col >> 9; mm = col & 511;
                                  bias = b_ioux[col] + b_iouh[col] + b_ious[col]; }
                else            { g = 3; mm = col - 1536; bias = b_fx[mm] + b_fh[mm]; }
                half4 hv;
                #pragma unroll
                for (int r = 0; r < 4; ++r) hv[r] = (_Float16)(v[r] + bias);
                *(half4*)(pre + ((((size_t)tt * 4 + g) * 512 + mm) * 64 + b)) = hv;
            } else {
                int mm = col - 2048;
                float bias = b_fxs[mm] + b_fs[mm];
                half4 hv;
                #pragma unroll
                for (int r = 0; r < 4; ++r) {
                    float s  = sigmoidf_fast(v[r] + bias);
                    float sc = smc[((size_t)(tt * 64 + b + r)) * 512 + mm];
                    hv[r] = (_Float16)(s * sc);
                }
                *(half4*)(addc + (((size_t)tt * 512 + mm) * 64 + b)) = hv;
            }
        }
    }
}

// ---------------- Phase B: persistent recurrent kernel ----------------------
// 64 WGs x 256 threads. WG owns m in [wg*8, wg*8+8); wave v owns b-tile
// [v*16, v*16+16). N-slice = 32 cols: {i x8, o x8} (ntile0), {u x8, f x8}
// (ntile1). Lane l: c8=(l>>3)&1 splits lane pairs l / l^8 into (i,u)/(o,f).
// Weights in registers. Cross-WG traffic (h, flags) is sc0+sc1 inline asm
// (device-coherent, NO buffer_inv/buffer_wbl2). Ordering: vmcnt(0) only.

__global__ __launch_bounds__(256, 1)
void lstm_rec(const _Float16* __restrict__ Wr, const _Float16* __restrict__ pre,
              const _Float16* __restrict__ addc, const float* __restrict__ c0,
              _Float16* __restrict__ hbuf, float* __restrict__ out,
              int* __restrict__ flags) {
    const int wg = blockIdx.x;
    const int tid = threadIdx.x;
    const int wv = tid >> 6, lane = tid & 63;
    const int lr = lane & 15, lq = lane >> 4;
    const int c8 = (lane >> 3) & 1;
    const int m  = wg * 8 + (lane & 7);
    const int b0 = wv * 16 + lq * 4;

    // recurrent weights -> registers (once)
    half8 bfr[2][16];
    #pragma unroll
    for (int nt = 0; nt < 2; ++nt)
        #pragma unroll
        for (int kk = 0; kk < 16; ++kk)
            bfr[nt][kk] = *(const half8*)(Wr + ((size_t)(wg * 32 + nt * 16 + lr)) * 512
                                          + kk * 32 + lq * 8);

    float c[4];
    #pragma unroll
    for (int r = 0; r < 4; ++r) c[r] = c0[(size_t)(b0 + r) * 512 + m];

    half4 pv[2], av;
    #pragma unroll
    for (int nt = 0; nt < 2; ++nt) {
        int g = nt * 2 + c8;
        pv[nt] = *(const half4*)(pre + (((size_t)0 * 4 + g) * 512 + m) * 64 + b0);
    }
    av = *(const half4*)(addc + ((size_t)0 * 512 + m) * 64 + b0);

    const int* myflag = flags + lane * FLAG_STRIDE;   // lane i polls WG i's flag

    for (int t = 0; t < T_STEPS; ++t) {
        const _Float16* hr = hbuf + (size_t)(t & 1) * B_DIM * M_DIM;
        const _Float16* bp = hr + (size_t)(wv * 16 + lr) * 512 + lq * 8;

        // acc init from CURRENT step's pre/addc — BEFORE prefetch clobbers
        f32x4 acc[2];
        #pragma unroll
        for (int nt = 0; nt < 2; ++nt)
            #pragma unroll
            for (int r = 0; r < 4; ++r) acc[nt][r] = (float)pv[nt][r];
        half4 avc = av;

        // prefetch next step's pre/addc (normal cached; in flight during gather)
        if (t + 1 < T_STEPS) {
            #pragma unroll
            for (int nt = 0; nt < 2; ++nt) {
                int g = nt * 2 + c8;
                pv[nt] = *(const half4*)(pre + (((size_t)(t + 1) * 4 + g) * 512 + m) * 64 + b0);
            }
            av = *(const half4*)(addc + ((size_t)(t + 1) * 512 + m) * 64 + b0);
        }

        // h gather: 16 device-coherent 16B loads + waitcnt in ONE asm block
        // (monolithic: no compiler-inserted reads of not-ready dest regs)
        half8 af[16];
        asm volatile(
            "global_load_dwordx4 %0,  %16, off sc0 sc1\n\t"
            "global_load_dwordx4 %1,  %16, off offset:64 sc0 sc1\n\t"
            "global_load_dwordx4 %2,  %16, off offset:128 sc0 sc1\n\t"
            "global_load_dwordx4 %3,  %16, off offset:192 sc0 sc1\n\t"
            "global_load_dwordx4 %4,  %16, off offset:256 sc0 sc1\n\t"
            "global_load_dwordx4 %5,  %16, off offset:320 sc0 sc1\n\t"
            "global_load_dwordx4 %6,  %16, off offset:384 sc0 sc1\n\t"
            "global_load_dwordx4 %7,  %16, off offset:448 sc0 sc1\n\t"
            "global_load_dwordx4 %8,  %16, off offset:512 sc0 sc1\n\t"
            "global_load_dwordx4 %9,  %16, off offset:576 sc0 sc1\n\t"
            "global_load_dwordx4 %10, %16, off offset:640 sc0 sc1\n\t"
            "global_load_dwordx4 %11, %16, off offset:704 sc0 sc1\n\t"
            "global_load_dwordx4 %12, %16, off offset:768 sc0 sc1\n\t"
            "global_load_dwordx4 %13, %16, off offset:832 sc0 sc1\n\t"
            "global_load_dwordx4 %14, %16, off offset:896 sc0 sc1\n\t"
            "global_load_dwordx4 %15, %16, off offset:960 sc0 sc1\n\t"
            "s_waitcnt vmcnt(0)"
            : "=&v"(af[0]),  "=&v"(af[1]),  "=&v"(af[2]),  "=&v"(af[3]),
              "=&v"(af[4]),  "=&v"(af[5]),  "=&v"(af[6]),  "=&v"(af[7]),
              "=&v"(af[8]),  "=&v"(af[9]),  "=&v"(af[10]), "=&v"(af[11]),
              "=&v"(af[12]), "=&v"(af[13]), "=&v"(af[14]), "=&v"(af[15])
            : "v"(bp)
            : "memory");

        #pragma unroll
        for (int kk = 0; kk < 16; ++kk) {
            acc[0] = __builtin_amdgcn_mfma_f32_16x16x32_f16(af[kk], bfr[0][kk], acc[0], 0, 0, 0);
            acc[1] = __builtin_amdgcn_mfma_f32_16x16x32_f16(af[kk], bfr[1][kk], acc[1], 0, 0, 0);
        }

        float hnew[4];
        #pragma unroll
        for (int r = 0; r < 4; ++r) {
            float raw0 = acc[0][r];   // laneA: i_raw  | laneB: o_raw
            float raw1 = acc[1][r];   // laneA: u_raw  | laneB: f_raw
            float s0 = sigmoidf_fast(raw0);
            float v1 = c8 ? sigmoidf_fast(raw1) : tanhf_fast(raw1);
            float sf = __shfl_xor(v1, 8);               // laneA <- sig(f)
            float cn = s0 * v1 + sf * c[r] + (float)avc[r];   // valid on laneA
            float tc = tanhf_fast(cn);
            float tcx = __shfl_xor(tc, 8);              // laneB <- tanh(c_new)
            if (!c8) c[r] = cn;
            hnew[r] = s0 * tcx;                         // valid on laneB
        }

        if (t == T_STEPS - 1) {
            if (c8) {
                #pragma unroll
                for (int r = 0; r < 4; ++r)
                    out[((size_t)t * B_DIM + b0 + r) * M_DIM + m] = hnew[r];
            }
            size_t base = (size_t)T_STEPS * B_DIM * M_DIM;
            if (!c8) {
                #pragma unroll
                for (int r = 0; r < 4; ++r)
                    out[base + (size_t)(b0 + r) * M_DIM + m] = c[r];
            } else {
                #pragma unroll
                for (int r = 0; r < 4; ++r)
                    out[base + (size_t)B_DIM * M_DIM + (size_t)(b0 + r) * M_DIM + m] = hnew[r];
            }
        } else {
            // publish h for t+1: device-coherent 2B stores (bypass L1/L2)
            _Float16* hw = hbuf + (size_t)((t + 1) & 1) * B_DIM * M_DIM;
            if (c8) {
                #pragma unroll
                for (int r = 0; r < 4; ++r) {
                    _Float16 hv = (_Float16)hnew[r];
                    unsigned int u = (unsigned int)__builtin_bit_cast(unsigned short, hv);
                    asm volatile("global_store_short %0, %1, off sc0 sc1"
                                 :: "v"(hw + (size_t)(b0 + r) * M_DIM + m), "v"(u)
                                 : "memory");
                }
            }
            asm volatile("s_waitcnt vmcnt(0)" ::: "memory");  // h at coherence point
            __syncthreads();                                  // whole WG published
            if (tid == 0) {
                unsigned int fv = (unsigned int)(t + 1);
                asm volatile("global_store_dword %0, %1, off sc0 sc1"
                             :: "v"(flags + wg * FLAG_STRIDE), "v"(fv) : "memory");
            }
            // out[t] stores drain inside the wait window (normal cached)
            if (c8) {
                #pragma unroll
                for (int r = 0; r < 4; ++r)
                    out[((size_t)t * B_DIM + b0 + r) * M_DIM + m] = hnew[r];
            }
            // poll all 64 flags, one per lane (load+wait in one asm block)
            const int target = t + 1;
            while (true) {
                int v;
                asm volatile("global_load_dword %0, %1, off sc0 sc1\n\t"
                             "s_waitcnt vmcnt(0)"
                             : "=v"(v) : "v"(myflag) : "memory");
                if (__all(v >= target)) break;
                __builtin_amdgcn_s_sleep(1);
            }
        }
    }
}

// ---------------------------------------------------------------------------

extern "C" void kernel_launch(void* const* d_in, const int* in_sizes, int n_in,
                              void* d_out, int out_size, void* d_ws, size_t ws_size,
                              hipStream_t stream) {
    const float* inputs  = (const float*)d_in[0];
    const float* smc     = (const float*)d_in[1];
    const float* smh     = (const float*)d_in[2];
    const float* c0      = (const float*)d_in[3];
    const float* h0      = (const float*)d_in[4];
    const float* W_ioux  = (const float*)d_in[5];
    const float* b_ioux  = (const float*)d_in[6];
    const float* W_iouh  = (const float*)d_in[7];
    const float* b_iouh  = (const float*)d_in[8];
    const float* W_ious  = (const float*)d_in[9];
    const float* b_ious  = (const float*)d_in[10];
    const float* W_fx    = (const float*)d_in[11];
    const float* b_fx    = (const float*)d_in[12];
    const float* W_fxs   = (const float*)d_in[13];
    const float* b_fxs   = (const float*)d_in[14];
    const float* W_fh    = (const float*)d_in[15];
    const float* b_fh    = (const float*)d_in[16];
    const float* W_fs    = (const float*)d_in[17];
    const float* b_fs    = (const float*)d_in[18];

    char* ws = (char*)d_ws;
    size_t off = 0;
    auto alloc = [&](size_t bytes) {
        char* p = ws + off;
        off = (off + bytes + 255) & ~(size_t)255;
        return p;
    };
    _Float16* XS   = (_Float16*)alloc((size_t)MA * KA * 2);          // 32 MiB
    _Float16* Wc   = (_Float16*)alloc((size_t)NA * KA * 2);          // 5 MiB
    _Float16* Wr   = (_Float16*)alloc((size_t)2048 * 512 * 2);       // 2 MiB
    _Float16* hb   = (_Float16*)alloc((size_t)2 * B_DIM * M_DIM * 2);// 128 KiB
    _Float16* pre  = (_Float16*)alloc((size_t)T_STEPS * 4 * 512 * 64 * 2); // 64 MiB
    _Float16* addc = (_Float16*)alloc((size_t)T_STEPS * 512 * 64 * 2);     // 16 MiB
    int* flags     = (int*)alloc(NWG_REC * FLAG_STRIDE * sizeof(int));     // 8 KiB
    if (off > ws_size) return;  // insufficient workspace -> visible failure

    hipMemsetAsync(flags, 0, NWG_REC * FLAG_STRIDE * sizeof(int), stream);
    conv_xs <<<MA * KA / 8 / 256, 256, 0, stream>>>(inputs, smh, XS);
    conv_w  <<<NA * KA / 8 / 256, 256, 0, stream>>>(W_ioux, W_ious, W_fx, W_fxs, W_fs, Wc);
    conv_wr <<<2048 * 512 / 8 / 256, 256, 0, stream>>>(W_iouh, W_fh, Wr);
    conv_h0 <<<B_DIM * M_DIM / 8 / 256, 256, 0, stream>>>(h0, hb);
    gemm_pre<<<2560, 256, 0, stream>>>(XS, Wc, b_ioux, b_iouh, b_ious, b_fx, b_fh,
                                       b_fxs, b_fs, smc, pre, addc);
    lstm_rec<<<NWG_REC, 256, 0, stream>>>(Wr, pre, addc, c0, hb, (float*)d_out, flags);
}